// Round 1
// baseline (360.089 us; speedup 1.0000x reference)
//
#include <hip/hip_runtime.h>
#include <cstdint>
#include <cstddef>

typedef unsigned short u16;
typedef short bf16x8 __attribute__((ext_vector_type(8)));
typedef float f32x4 __attribute__((ext_vector_type(4)));

#define MFMA(a,b,c) __builtin_amdgcn_mfma_f32_16x16x32_bf16(a,b,c,0,0,0)

__device__ __forceinline__ u16 f2bf(float f) {
  unsigned u = __builtin_bit_cast(unsigned, f);
  u += 0x7fffu + ((u >> 16) & 1u);
  return (u16)(u >> 16);
}
__device__ __forceinline__ float bf2f(u16 b) {
  return __builtin_bit_cast(float, (unsigned)b << 16);
}
__device__ __forceinline__ void gl_lds16(const void* g, void* l) {
  __builtin_amdgcn_global_load_lds(
      (const __attribute__((address_space(1))) void*)g,
      (__attribute__((address_space(3))) void*)l, 16, 0, 0);
}

// ---------------- f32 -> bf16 convert ----------------
__global__ __launch_bounds__(256) void cvt_bf16(const float* __restrict__ in,
                                                u16* __restrict__ out, int n) {
  int idx = (blockIdx.x * 256 + threadIdx.x) * 4;
  if (idx < n) {
    float4 v = *(const float4*)(in + idx);
    u16 o0 = f2bf(v.x), o1 = f2bf(v.y), o2 = f2bf(v.z), o3 = f2bf(v.w);
    ushort4 o = {o0, o1, o2, o3};
    *(ushort4*)(out + idx) = o;
  }
}

// ---------------- RoPE cos/sin table: [T=2048][64] f32 ----------------
__global__ __launch_bounds__(256) void rope_table(float* __restrict__ ctab,
                                                  float* __restrict__ stab) {
  int i = blockIdx.x * 256 + threadIdx.x;  // 0 .. 131071
  int t = i >> 6, f = i & 63;
  float inv_freq = powf(10000.0f, -(2.0f * f) / 128.0f);
  float ang = (float)t * inv_freq;
  ctab[i] = cosf(ang);
  stab[i] = sinf(ang);
}

// ---------------- NT GEMM: A[M,K] bf16 rm, B[N,K] bf16 rm -> C[M,N] ----------------
// m97 structure: 128x128 tile, BK=64, 4 waves (2x2), global_load_lds w=16.
template <int OUT_F32>
__global__ __launch_bounds__(256) void gemm_nt(const u16* __restrict__ A,
                                               const u16* __restrict__ Bw,
                                               void* __restrict__ Cout,
                                               int M, int N, int K) {
  __shared__ u16 As[128 * 64];
  __shared__ u16 Bs[128 * 64];
  const int tid = threadIdx.x;
  const int lane = tid & 63;
  const int wv = tid >> 6;
  const int l16 = lane & 15, lhi = lane >> 4;
  const int m0 = blockIdx.y * 128;
  const int n0 = blockIdx.x * 128;
  const int wm = (wv >> 1) * 64;
  const int wn = (wv & 1) * 64;

  f32x4 acc[4][4] = {};

  const int srow = (lane >> 3);        // 0..7 within chunk
  const int scolb = (lane & 7) * 16;   // byte col within 128B row

  for (int k0 = 0; k0 < K; k0 += 64) {
#pragma unroll
    for (int i = 0; i < 4; ++i) {
      int c = wv + 4 * i;              // wave-uniform chunk 0..15
      int row = c * 8 + srow;
      const char* gA = (const char*)A + ((size_t)(m0 + row) * K + k0) * 2 + scolb;
      gl_lds16(gA, (char*)As + c * 1024);
      const char* gB = (const char*)Bw + ((size_t)(n0 + row) * K + k0) * 2 + scolb;
      gl_lds16(gB, (char*)Bs + c * 1024);
    }
    __syncthreads();
#pragma unroll
    for (int kk = 0; kk < 2; ++kk) {
      bf16x8 af[4], bfr[4];
#pragma unroll
      for (int mi = 0; mi < 4; ++mi)
        af[mi] = *(const bf16x8*)&As[(wm + mi * 16 + l16) * 64 + kk * 32 + lhi * 8];
#pragma unroll
      for (int ni = 0; ni < 4; ++ni)
        bfr[ni] = *(const bf16x8*)&Bs[(wn + ni * 16 + l16) * 64 + kk * 32 + lhi * 8];
#pragma unroll
      for (int mi = 0; mi < 4; ++mi)
#pragma unroll
        for (int ni = 0; ni < 4; ++ni)
          acc[mi][ni] = MFMA(af[mi], bfr[ni], acc[mi][ni]);
    }
    __syncthreads();
  }
#pragma unroll
  for (int mi = 0; mi < 4; ++mi)
#pragma unroll
    for (int ni = 0; ni < 4; ++ni) {
      int col = n0 + wn + ni * 16 + l16;
#pragma unroll
      for (int j = 0; j < 4; ++j) {
        int row = m0 + wm + mi * 16 + lhi * 4 + j;
        float v = acc[mi][ni][j];
        if (OUT_F32)
          ((float*)Cout)[(size_t)row * N + col] = v;
        else
          ((u16*)Cout)[(size_t)row * N + col] = f2bf(v);
      }
    }
}

// ---------------- RoPE + L2 norm + gamma; [B*T, nh*128] -> [B, nh, T, 128] ----------------
__global__ __launch_bounds__(256) void rope_norm(const u16* __restrict__ raw,
                                                 u16* __restrict__ out,
                                                 const float* __restrict__ ctab,
                                                 const float* __restrict__ stab,
                                                 const float* __restrict__ gamma,
                                                 int nh) {
  int gw = blockIdx.x * 4 + (threadIdx.x >> 6);
  int lane = threadIdx.x & 63;
  int h = gw % nh;
  int bt = gw / nh;               // 0..4095
  int t = bt & 2047, b = bt >> 11;
  const u16* r = raw + (size_t)bt * ((size_t)nh * 128) + (size_t)h * 128;
  float q1 = bf2f(r[lane]), q2 = bf2f(r[lane + 64]);
  float c = ctab[t * 64 + lane], s = stab[t * 64 + lane];
  float e1 = q1 * c - q2 * s;
  float e2 = q2 * c + q1 * s;
  float ss = e1 * e1 + e2 * e2;
#pragma unroll
  for (int off = 1; off < 64; off <<= 1) ss += __shfl_xor(ss, off);
  float inv = 1.0f / (sqrtf(ss) + 1e-6f);
  size_t ob = (((size_t)(b * nh + h)) * 2048 + t) * 128;
  out[ob + lane]      = f2bf(e1 * inv * gamma[lane]);
  out[ob + lane + 64] = f2bf(e2 * inv * gamma[lane + 64]);
}

// ---------------- V transpose: [B*T, HK*128] -> [B, HK, 128, T] ----------------
__global__ __launch_bounds__(256) void transpose_v(const u16* __restrict__ vraw,
                                                   u16* __restrict__ vt) {
  __shared__ u16 tile[32][33];
  int t0 = blockIdx.x * 32, d0 = blockIdx.y * 32;
  int bh = blockIdx.z;
  int b = bh >> 2, hk = bh & 3;
  int tx = threadIdx.x & 31, ty = threadIdx.x >> 5;  // ty 0..7
#pragma unroll
  for (int i = 0; i < 4; ++i) {
    int r = ty + i * 8;
    tile[r][tx] = vraw[((size_t)(b * 2048 + t0 + r)) * 512 + hk * 128 + d0 + tx];
  }
  __syncthreads();
#pragma unroll
  for (int i = 0; i < 4; ++i) {
    int r = ty + i * 8;
    vt[((size_t)((b * 4 + hk) * 128 + d0 + r)) * 2048 + t0 + tx] = tile[tx][r];
  }
}

// ---------------- flash attention, sliding window 1024 ----------------
// grid: (T/64, B*H); block 256 (4 waves, 16 q-rows each)
__global__ __launch_bounds__(256) void attn_kernel(const u16* __restrict__ Qr,
                                                   const u16* __restrict__ Kr,
                                                   const u16* __restrict__ Vt,
                                                   u16* __restrict__ Yt) {
  __shared__ u16 Ks[32 * 128];    // XOR-swizzled rows
  __shared__ u16 Vs[128 * 40];    // [d][s] stride 40 shorts (80B)
  __shared__ u16 Ps[4 * 16 * 40]; // per-wave P, stride 40
  const int tid = threadIdx.x;
  const int lane = tid & 63;
  const int wv = tid >> 6;
  const int l16 = lane & 15, lhi = lane >> 4;
  const int bh = blockIdx.y;
  const int b = bh >> 4, h = bh & 15;
  const int hk = h >> 2;
  const int q0b = blockIdx.x * 64;
  const int q0w = q0b + wv * 16;

  const u16* qbase = Qr + (((size_t)bh) * 2048 + q0w + l16) * 128;
  bf16x8 qf[4];
#pragma unroll
  for (int dc = 0; dc < 4; ++dc)
    qf[dc] = *(const bf16x8*)(qbase + dc * 32 + lhi * 8);

  const char* kg = (const char*)(Kr + ((size_t)(b * 4 + hk)) * 2048 * 128);
  const u16* vg = Vt + ((size_t)(b * 4 + hk)) * 2048 * 128;  // [128][2048]

  float m_r[4] = {-INFINITY, -INFINITY, -INFINITY, -INFINITY};
  float l_r[4] = {0.f, 0.f, 0.f, 0.f};
  f32x4 oacc[8] = {};

  int s_lo = q0b - 1024; if (s_lo < 0) s_lo = 0;
  const int s_end = q0b + 64;
  const float sc = 0.08838834764831845f;  // 1/sqrt(128)

  for (int s0 = s_lo; s0 < s_end; s0 += 32) {
    // stage K via global_load_lds with source-side XOR swizzle
#pragma unroll
    for (int i = 0; i < 2; ++i) {
      int c = wv + 4 * i;              // chunk 0..7, 1KB each (4 rows)
      int row = c * 4 + lhi;
      int colb = l16 * 16;
      int srcb = colb ^ ((row & 7) << 4);
      gl_lds16(kg + (size_t)(s0 + row) * 256 + srcb, (char*)Ks + c * 1024);
    }
    // stage V (reg-staged, padded stride)
#pragma unroll
    for (int i = 0; i < 2; ++i) {
      int idx = i * 256 + tid;
      int d = idx >> 2, s4 = idx & 3;
      int4 val = *(const int4*)(vg + (size_t)d * 2048 + s0 + s4 * 8);
      *(int4*)&Vs[d * 40 + s4 * 8] = val;
    }
    __syncthreads();
    // QK^T
    f32x4 sacc[2] = {};
#pragma unroll
    for (int n = 0; n < 2; ++n) {
      int row = n * 16 + l16;
#pragma unroll
      for (int dc = 0; dc < 4; ++dc) {
        int colb = ((dc * 32 + lhi * 8) * 2) ^ ((row & 7) << 4);
        bf16x8 kf = *(const bf16x8*)((const char*)Ks + row * 256 + colb);
        sacc[n] = MFMA(qf[dc], kf, sacc[n]);
      }
    }
    // mask + online softmax (C/D layout: row=(lhi)*4+j, col=l16)
    float sval[2][4];
    float mt[4] = {-INFINITY, -INFINITY, -INFINITY, -INFINITY};
#pragma unroll
    for (int n = 0; n < 2; ++n)
#pragma unroll
      for (int j = 0; j < 4; ++j) {
        int q = q0w + lhi * 4 + j;
        int s = s0 + n * 16 + l16;
        float v = sacc[n][j] * sc;
        int diff = q - s;
        if (diff < 0 || diff > 1024) v = -INFINITY;
        sval[n][j] = v;
        mt[j] = fmaxf(mt[j], v);
      }
#pragma unroll
    for (int off = 1; off < 16; off <<= 1)
#pragma unroll
      for (int j = 0; j < 4; ++j)
        mt[j] = fmaxf(mt[j], __shfl_xor(mt[j], off));
    float msub[4];
#pragma unroll
    for (int j = 0; j < 4; ++j) {
      float mn = fmaxf(m_r[j], mt[j]);
      float ms = (mn == -INFINITY) ? 0.f : mn;
      float scale = __expf(m_r[j] - ms);
      l_r[j] *= scale;
      m_r[j] = mn;
      msub[j] = ms;
#pragma unroll
      for (int dt = 0; dt < 8; ++dt) oacc[dt][j] *= scale;
    }
    float rowsum[4] = {0.f, 0.f, 0.f, 0.f};
#pragma unroll
    for (int n = 0; n < 2; ++n)
#pragma unroll
      for (int j = 0; j < 4; ++j) {
        float p = __expf(sval[n][j] - msub[j]);
        rowsum[j] += p;
        Ps[wv * 640 + (lhi * 4 + j) * 40 + n * 16 + l16] = f2bf(p);
      }
#pragma unroll
    for (int off = 1; off < 16; off <<= 1)
#pragma unroll
      for (int j = 0; j < 4; ++j)
        rowsum[j] += __shfl_xor(rowsum[j], off);
#pragma unroll
    for (int j = 0; j < 4; ++j) l_r[j] += rowsum[j];
    __syncthreads();
    // PV
    bf16x8 pf = *(const bf16x8*)&Ps[wv * 640 + l16 * 40 + lhi * 8];
#pragma unroll
    for (int dt = 0; dt < 8; ++dt) {
      bf16x8 vf = *(const bf16x8*)&Vs[(dt * 16 + l16) * 40 + lhi * 8];
      oacc[dt] = MFMA(pf, vf, oacc[dt]);
    }
    __syncthreads();
  }
  // epilogue: y_tmp[B*T, H*128]
#pragma unroll
  for (int j = 0; j < 4; ++j) {
    float inv = 1.0f / l_r[j];
    int q = q0w + lhi * 4 + j;
    size_t rowbase = ((size_t)(b * 2048 + q)) * 2048 + (size_t)h * 128;
#pragma unroll
    for (int dt = 0; dt < 8; ++dt)
      Yt[rowbase + dt * 16 + l16] = f2bf(oacc[dt][j] * inv);
  }
}

extern "C" void kernel_launch(void* const* d_in, const int* in_sizes, int n_in,
                              void* d_out, int out_size, void* d_ws, size_t ws_size,
                              hipStream_t stream) {
  (void)in_sizes; (void)n_in; (void)out_size; (void)ws_size;
  const float* x  = (const float*)d_in[0];
  const float* wq = (const float*)d_in[1];
  const float* wk = (const float*)d_in[2];
  const float* wv = (const float*)d_in[3];
  const float* wo = (const float*)d_in[4];
  const float* gq = (const float*)d_in[5];
  const float* gk = (const float*)d_in[6];
  float* out = (float*)d_out;
  char* ws = (char*)d_ws;

  size_t off = 0;
  auto alloc = [&](size_t bytes) {
    size_t o = off;
    off += (bytes + 255) & ~(size_t)255;
    return o;
  };
  u16* xb   = (u16*)(ws + alloc((size_t)4096 * 2048 * 2));
  u16* wqb  = (u16*)(ws + alloc((size_t)2048 * 2048 * 2));
  u16* wkb  = (u16*)(ws + alloc((size_t)512 * 2048 * 2));
  u16* wvb  = (u16*)(ws + alloc((size_t)512 * 2048 * 2));
  u16* wob  = (u16*)(ws + alloc((size_t)2048 * 2048 * 2));
  u16* qraw = (u16*)(ws + alloc((size_t)4096 * 2048 * 2));  // reused as y_tmp
  u16* kraw = (u16*)(ws + alloc((size_t)4096 * 512 * 2));
  u16* vraw = (u16*)(ws + alloc((size_t)4096 * 512 * 2));
  u16* qr   = (u16*)(ws + alloc((size_t)4096 * 2048 * 2));
  u16* kr   = (u16*)(ws + alloc((size_t)4096 * 512 * 2));
  u16* vt   = (u16*)(ws + alloc((size_t)4096 * 512 * 2));
  float* ctab = (float*)(ws + alloc((size_t)2048 * 64 * 4));
  float* stab = (float*)(ws + alloc((size_t)2048 * 64 * 4));
  u16* ytmp = qraw;

  // converts
  cvt_bf16<<<8192, 256, 0, stream>>>(x, xb, 8388608);
  cvt_bf16<<<4096, 256, 0, stream>>>(wq, wqb, 4194304);
  cvt_bf16<<<1024, 256, 0, stream>>>(wk, wkb, 1048576);
  cvt_bf16<<<1024, 256, 0, stream>>>(wv, wvb, 1048576);
  cvt_bf16<<<4096, 256, 0, stream>>>(wo, wob, 4194304);
  rope_table<<<512, 256, 0, stream>>>(ctab, stab);

  // projections
  gemm_nt<0><<<dim3(16, 32), 256, 0, stream>>>(xb, wqb, qraw, 4096, 2048, 2048);
  gemm_nt<0><<<dim3(4, 32), 256, 0, stream>>>(xb, wkb, kraw, 4096, 512, 2048);
  gemm_nt<0><<<dim3(4, 32), 256, 0, stream>>>(xb, wvb, vraw, 4096, 512, 2048);

  // rope + qk-norm, V transpose
  rope_norm<<<16384, 256, 0, stream>>>(qraw, qr, ctab, stab, gq, 16);
  rope_norm<<<4096, 256, 0, stream>>>(kraw, kr, ctab, stab, gk, 4);
  transpose_v<<<dim3(64, 4, 8), 256, 0, stream>>>(vraw, vt);

  // attention
  attn_kernel<<<dim3(32, 32), 256, 0, stream>>>(qr, kr, vt, ytmp);

  // output projection (f32 out)
  gemm_nt<1><<<dim3(16, 32), 256, 0, stream>>>(ytmp, wob, out, 4096, 2048, 2048);
}

// Round 2
// 279.962 us; speedup vs baseline: 1.2862x; 1.2862x over previous
//
#include <hip/hip_runtime.h>
#include <cstdint>
#include <cstddef>

typedef unsigned short u16;
typedef short bf16x8 __attribute__((ext_vector_type(8)));
typedef float f32x4 __attribute__((ext_vector_type(4)));

#define MFMA(a,b,c) __builtin_amdgcn_mfma_f32_16x16x32_bf16(a,b,c,0,0,0)

__device__ __forceinline__ u16 f2bf(float f) {
  unsigned u = __builtin_bit_cast(unsigned, f);
  u += 0x7fffu + ((u >> 16) & 1u);
  return (u16)(u >> 16);
}
__device__ __forceinline__ float bf2f(u16 b) {
  return __builtin_bit_cast(float, (unsigned)b << 16);
}
__device__ __forceinline__ void gl_lds16(const void* g, void* l) {
  __builtin_amdgcn_global_load_lds(
      (const __attribute__((address_space(1))) void*)g,
      (__attribute__((address_space(3))) void*)l, 16, 0, 0);
}

// ---------------- f32 -> bf16 convert ----------------
__global__ __launch_bounds__(256) void cvt_bf16(const float* __restrict__ in,
                                                u16* __restrict__ out, int n) {
  int idx = (blockIdx.x * 256 + threadIdx.x) * 4;
  if (idx < n) {
    float4 v = *(const float4*)(in + idx);
    u16 o0 = f2bf(v.x), o1 = f2bf(v.y), o2 = f2bf(v.z), o3 = f2bf(v.w);
    ushort4 o = {o0, o1, o2, o3};
    *(ushort4*)(out + idx) = o;
  }
}

// ---------------- RoPE cos/sin table: [T=2048][64] f32 ----------------
__global__ __launch_bounds__(256) void rope_table(float* __restrict__ ctab,
                                                  float* __restrict__ stab) {
  int i = blockIdx.x * 256 + threadIdx.x;  // 0 .. 131071
  int t = i >> 6, f = i & 63;
  float inv_freq = powf(10000.0f, -(2.0f * f) / 128.0f);
  float ang = (float)t * inv_freq;
  ctab[i] = cosf(ang);
  stab[i] = sinf(ang);
}

// ---------------- NT GEMM: A[M,K] bf16 rm, B[N,K] bf16 rm -> C[M,N] ----------------
template <int OUT_F32>
__global__ __launch_bounds__(256) void gemm_nt(const u16* __restrict__ A,
                                               const u16* __restrict__ Bw,
                                               void* __restrict__ Cout,
                                               int M, int N, int K) {
  __shared__ u16 As[128 * 64];
  __shared__ u16 Bs[128 * 64];
  const int tid = threadIdx.x;
  const int lane = tid & 63;
  const int wv = tid >> 6;
  const int l16 = lane & 15, lhi = lane >> 4;
  const int m0 = blockIdx.y * 128;
  const int n0 = blockIdx.x * 128;
  const int wm = (wv >> 1) * 64;
  const int wn = (wv & 1) * 64;

  f32x4 acc[4][4] = {};

  const int srow = (lane >> 3);        // 0..7 within chunk
  const int scolb = (lane & 7) * 16;   // byte col within 128B row

  for (int k0 = 0; k0 < K; k0 += 64) {
#pragma unroll
    for (int i = 0; i < 4; ++i) {
      int c = wv + 4 * i;              // wave-uniform chunk 0..15
      int row = c * 8 + srow;
      const char* gA = (const char*)A + ((size_t)(m0 + row) * K + k0) * 2 + scolb;
      gl_lds16(gA, (char*)As + c * 1024);
      const char* gB = (const char*)Bw + ((size_t)(n0 + row) * K + k0) * 2 + scolb;
      gl_lds16(gB, (char*)Bs + c * 1024);
    }
    __syncthreads();
#pragma unroll
    for (int kk = 0; kk < 2; ++kk) {
      bf16x8 af[4], bfr[4];
#pragma unroll
      for (int mi = 0; mi < 4; ++mi)
        af[mi] = *(const bf16x8*)&As[(wm + mi * 16 + l16) * 64 + kk * 32 + lhi * 8];
#pragma unroll
      for (int ni = 0; ni < 4; ++ni)
        bfr[ni] = *(const bf16x8*)&Bs[(wn + ni * 16 + l16) * 64 + kk * 32 + lhi * 8];
#pragma unroll
      for (int mi = 0; mi < 4; ++mi)
#pragma unroll
        for (int ni = 0; ni < 4; ++ni)
          acc[mi][ni] = MFMA(af[mi], bfr[ni], acc[mi][ni]);
    }
    __syncthreads();
  }
#pragma unroll
  for (int mi = 0; mi < 4; ++mi)
#pragma unroll
    for (int ni = 0; ni < 4; ++ni) {
      int col = n0 + wn + ni * 16 + l16;
#pragma unroll
      for (int j = 0; j < 4; ++j) {
        int row = m0 + wm + mi * 16 + lhi * 4 + j;
        float v = acc[mi][ni][j];
        if (OUT_F32)
          ((float*)Cout)[(size_t)row * N + col] = v;
        else
          ((u16*)Cout)[(size_t)row * N + col] = f2bf(v);
      }
    }
}

// ---------------- RoPE + L2 norm + gamma ----------------
template <int NH>
__global__ __launch_bounds__(256) void rope_norm(const u16* __restrict__ raw,
                                                 u16* __restrict__ out,
                                                 const float* __restrict__ ctab,
                                                 const float* __restrict__ stab,
                                                 const float* __restrict__ gamma,
                                                 int stride, int coloff, float scale) {
  int gw = blockIdx.x * 4 + (threadIdx.x >> 6);
  int lane = threadIdx.x & 63;
  int h = gw & (NH - 1);
  int bt = gw / NH;               // 0..4095
  int t = bt & 2047, b = bt >> 11;
  const u16* r = raw + (size_t)bt * stride + coloff + (size_t)h * 128;
  float q1 = bf2f(r[lane]), q2 = bf2f(r[lane + 64]);
  float c = ctab[t * 64 + lane], s = stab[t * 64 + lane];
  float e1 = q1 * c - q2 * s;
  float e2 = q2 * c + q1 * s;
  float ss = e1 * e1 + e2 * e2;
#pragma unroll
  for (int off = 1; off < 64; off <<= 1) ss += __shfl_xor(ss, off);
  float inv = scale / (sqrtf(ss) + 1e-6f);
  size_t ob = (((size_t)(b * NH + h)) * 2048 + t) * 128;
  out[ob + lane]      = f2bf(e1 * inv * gamma[lane]);
  out[ob + lane + 64] = f2bf(e2 * inv * gamma[lane + 64]);
}

// ---------------- V transpose: qkv[B*T,3072] cols 2560.. -> [B, HK, 128, T] ----------------
__global__ __launch_bounds__(256) void transpose_v(const u16* __restrict__ qkv,
                                                   u16* __restrict__ vt) {
  __shared__ u16 tile[32][33];
  int t0 = blockIdx.x * 32, d0 = blockIdx.y * 32;
  int bh = blockIdx.z;
  int b = bh >> 2, hkk = bh & 3;
  int tx = threadIdx.x & 31, ty = threadIdx.x >> 5;  // ty 0..7
#pragma unroll
  for (int i = 0; i < 4; ++i) {
    int r = ty + i * 8;
    tile[r][tx] = qkv[((size_t)(b * 2048 + t0 + r)) * 3072 + 2560 + hkk * 128 + d0 + tx];
  }
  __syncthreads();
#pragma unroll
  for (int i = 0; i < 4; ++i) {
    int r = ty + i * 8;
    vt[((size_t)((b * 4 + hkk) * 128 + d0 + r)) * 2048 + t0 + tx] = tile[tx][r];
  }
}

// ---------------- flash attention, sliding window 1024, KVBLK=64, double-buffered ----------------
// grid: (T/64, B*H); block 256 (4 waves, 16 q-rows each)
__global__ __launch_bounds__(256) void attn_kernel(const u16* __restrict__ Qr,
                                                   const u16* __restrict__ Kr,
                                                   const u16* __restrict__ Vt,
                                                   u16* __restrict__ Yt) {
  __shared__ u16 Ks[2][64 * 128];   // 16KB each, XOR-swizzled 256B rows
  __shared__ u16 Vs[2][128 * 64];   // 16KB each, XOR-swizzled 128B rows, [d][s]
  __shared__ u16 Ps[4][16 * 64];    // per-wave P, XOR-swizzled 128B rows
  const int tid = threadIdx.x;
  const int lane = tid & 63;
  const int wv = tid >> 6;
  const int l16 = lane & 15, lhi = lane >> 4;
  const int bh = blockIdx.y;
  const int b = bh >> 4, h = bh & 15;
  const int hk = h >> 2;
  const int q0b = blockIdx.x * 64;
  const int q0w = q0b + wv * 16;

  const u16* qbase = Qr + (((size_t)bh) * 2048 + q0w + l16) * 128;
  bf16x8 qf[4];
#pragma unroll
  for (int dc = 0; dc < 4; ++dc)
    qf[dc] = *(const bf16x8*)(qbase + dc * 32 + lhi * 8);

  const char* kg = (const char*)(Kr + ((size_t)(b * 4 + hk)) * 2048 * 128);
  const u16* vg = Vt + ((size_t)(b * 4 + hk)) * 2048 * 128;  // [128][2048]

  auto stage = [&](int buf, int s0) {
    // K tile: 64 rows x 256B. chunk=1KB=4 rows, chunks 0..15
#pragma unroll
    for (int i = 0; i < 4; ++i) {
      int c = wv + 4 * i;
      int row = c * 4 + lhi;
      int srcb = (l16 * 16) ^ ((row & 7) << 4);
      gl_lds16(kg + (size_t)(s0 + row) * 256 + srcb, (char*)Ks[buf] + c * 1024);
    }
    // V tile: 128 rows x 128B. chunk=1KB=8 rows
    int r8 = lane >> 3, c8 = lane & 7;
#pragma unroll
    for (int i = 0; i < 4; ++i) {
      int c = wv + 4 * i;
      int row = c * 8 + r8;
      int srcb = (c8 * 16) ^ ((r8 & 7) << 4);   // row&7 == r8
      gl_lds16((const char*)(vg + (size_t)row * 2048 + s0) + srcb,
               (char*)Vs[buf] + c * 1024);
    }
  };

  float msub[4] = {0.f, 0.f, 0.f, 0.f};
  float l_r[4] = {0.f, 0.f, 0.f, 0.f};
  f32x4 oacc[8] = {};

  int s_lo = q0b - 1024; if (s_lo < 0) s_lo = 0;
  const int nt = (q0b + 64 - s_lo) >> 6;

  stage(0, s_lo);
  __syncthreads();
  int cur = 0;
  for (int it = 0; it < nt; ++it) {
    const int s0 = s_lo + (it << 6);
    if (it + 1 < nt) stage(cur ^ 1, s0 + 64);
    // QK^T (16 MFMA)
    f32x4 sacc[4] = {};
    const char* ksb = (const char*)Ks[cur];
    __builtin_amdgcn_s_setprio(1);
#pragma unroll
    for (int n = 0; n < 4; ++n) {
      int row = n * 16 + l16;
#pragma unroll
      for (int dc = 0; dc < 4; ++dc) {
        bf16x8 kf = *(const bf16x8*)(ksb + row * 256 +
                                     ((dc * 64 + lhi * 16) ^ ((l16 & 7) << 4)));
        sacc[n] = MFMA(qf[dc], kf, sacc[n]);
      }
    }
    __builtin_amdgcn_s_setprio(0);
    // mask + tile max (C/D layout: row=lhi*4+j, col=l16)
    float sval[4][4];
    float mt[4] = {-INFINITY, -INFINITY, -INFINITY, -INFINITY};
#pragma unroll
    for (int n = 0; n < 4; ++n)
#pragma unroll
      for (int j = 0; j < 4; ++j) {
        int q = q0w + lhi * 4 + j;
        int s = s0 + n * 16 + l16;
        float v = sacc[n][j];
        if ((unsigned)(q - s) > 1024u) v = -INFINITY;
        sval[n][j] = v;
        mt[j] = fmaxf(mt[j], v);
      }
#pragma unroll
    for (int off = 1; off < 16; off <<= 1)
#pragma unroll
      for (int j = 0; j < 4; ++j)
        mt[j] = fmaxf(mt[j], __shfl_xor(mt[j], off));
    // T13: only rescale when tile max exceeds current base by >8
    bool need = false;
#pragma unroll
    for (int j = 0; j < 4; ++j) need = need || (mt[j] > msub[j] + 8.f);
    if (__any(need)) {
#pragma unroll
      for (int j = 0; j < 4; ++j) {
        float nb = fmaxf(msub[j], mt[j]);
        float sc2 = __expf(msub[j] - nb);
        l_r[j] *= sc2;
#pragma unroll
        for (int dt = 0; dt < 8; ++dt) oacc[dt][j] *= sc2;
        msub[j] = nb;
      }
    }
    // P = exp(s - base), write swizzled to LDS, rowsum
    char* psb = (char*)Ps[wv];
    float rs[4] = {0.f, 0.f, 0.f, 0.f};
#pragma unroll
    for (int n = 0; n < 4; ++n)
#pragma unroll
      for (int j = 0; j < 4; ++j) {
        float p = __expf(sval[n][j] - msub[j]);
        rs[j] += p;
        int R = lhi * 4 + j;
        *(u16*)(psb + R * 128 + (((n * 16 + l16) * 2) ^ ((R & 7) << 4))) = f2bf(p);
      }
#pragma unroll
    for (int off = 1; off < 16; off <<= 1)
#pragma unroll
      for (int j = 0; j < 4; ++j) rs[j] += __shfl_xor(rs[j], off);
#pragma unroll
    for (int j = 0; j < 4; ++j) l_r[j] += rs[j];
    // PV (16 MFMA)
    bf16x8 pf[2];
#pragma unroll
    for (int kk = 0; kk < 2; ++kk)
      pf[kk] = *(const bf16x8*)(psb + l16 * 128 +
                                ((kk * 64 + lhi * 16) ^ ((l16 & 7) << 4)));
    const char* vsb = (const char*)Vs[cur];
    __builtin_amdgcn_s_setprio(1);
#pragma unroll
    for (int dt = 0; dt < 8; ++dt) {
      int row = dt * 16 + l16;
#pragma unroll
      for (int kk = 0; kk < 2; ++kk) {
        bf16x8 vf = *(const bf16x8*)(vsb + row * 128 +
                                     ((kk * 64 + lhi * 16) ^ ((l16 & 7) << 4)));
        oacc[dt] = MFMA(pf[kk], vf, oacc[dt]);
      }
    }
    __builtin_amdgcn_s_setprio(0);
    __syncthreads();
    cur ^= 1;
  }
  // epilogue: ytmp[B*T, H*128]
#pragma unroll
  for (int j = 0; j < 4; ++j) {
    float inv = 1.0f / l_r[j];
    int q = q0w + lhi * 4 + j;
    size_t rowbase = ((size_t)(b * 2048 + q)) * 2048 + (size_t)h * 128;
#pragma unroll
    for (int dt = 0; dt < 8; ++dt)
      Yt[rowbase + dt * 16 + l16] = f2bf(oacc[dt][j] * inv);
  }
}

extern "C" void kernel_launch(void* const* d_in, const int* in_sizes, int n_in,
                              void* d_out, int out_size, void* d_ws, size_t ws_size,
                              hipStream_t stream) {
  (void)in_sizes; (void)n_in; (void)out_size; (void)ws_size;
  const float* x  = (const float*)d_in[0];
  const float* wq = (const float*)d_in[1];
  const float* wk = (const float*)d_in[2];
  const float* wv = (const float*)d_in[3];
  const float* wo = (const float*)d_in[4];
  const float* gq = (const float*)d_in[5];
  const float* gk = (const float*)d_in[6];
  float* out = (float*)d_out;
  char* ws = (char*)d_ws;

  size_t off = 0;
  auto alloc = [&](size_t bytes) {
    size_t o = off;
    off += (bytes + 255) & ~(size_t)255;
    return o;
  };
  u16* xb     = (u16*)(ws + alloc((size_t)4096 * 2048 * 2));
  u16* wqkvb  = (u16*)(ws + alloc((size_t)3072 * 2048 * 2));
  u16* wob    = (u16*)(ws + alloc((size_t)2048 * 2048 * 2));
  u16* qkvraw = (u16*)(ws + alloc((size_t)4096 * 3072 * 2));  // later reused as ytmp
  u16* qr     = (u16*)(ws + alloc((size_t)4096 * 2048 * 2));
  u16* kr     = (u16*)(ws + alloc((size_t)4096 * 512 * 2));
  u16* vt     = (u16*)(ws + alloc((size_t)4096 * 512 * 2));
  float* ctab = (float*)(ws + alloc((size_t)2048 * 64 * 4));
  float* stab = (float*)(ws + alloc((size_t)2048 * 64 * 4));
  u16* ytmp = qkvraw;  // safe: qkvraw fully consumed before attn writes

  const float sc = 0.08838834764831845f;  // 1/sqrt(128)

  // converts (weights fused into one [3072][2048] QKV weight)
  cvt_bf16<<<8192, 256, 0, stream>>>(x, xb, 8388608);
  cvt_bf16<<<4096, 256, 0, stream>>>(wq, wqkvb, 4194304);
  cvt_bf16<<<1024, 256, 0, stream>>>(wk, wqkvb + 4194304, 1048576);
  cvt_bf16<<<1024, 256, 0, stream>>>(wv, wqkvb + 4194304 + 1048576, 1048576);
  cvt_bf16<<<4096, 256, 0, stream>>>(wo, wob, 4194304);
  rope_table<<<512, 256, 0, stream>>>(ctab, stab);

  // fused QKV projection: [4096,2048] x [3072,2048]^T -> [4096,3072]
  gemm_nt<0><<<dim3(24, 32), 256, 0, stream>>>(xb, wqkvb, qkvraw, 4096, 3072, 2048);

  // rope + qk-norm (Q gets 1/sqrt(D) folded in), V transpose
  rope_norm<16><<<16384, 256, 0, stream>>>(qkvraw, qr, ctab, stab, gq, 3072, 0, sc);
  rope_norm<4><<<4096, 256, 0, stream>>>(qkvraw, kr, ctab, stab, gk, 3072, 2048, 1.0f);
  transpose_v<<<dim3(64, 4, 8), 256, 0, stream>>>(qkvraw, vt);

  // attention
  attn_kernel<<<dim3(32, 32), 256, 0, stream>>>(qr, kr, vt, ytmp);

  // output projection (f32 out)
  gemm_nt<1><<<dim3(16, 32), 256, 0, stream>>>(ytmp, wob, out, 4096, 2048, 2048);
}

// Round 3
// 247.303 us; speedup vs baseline: 1.4561x; 1.1321x over previous
//
#include <hip/hip_runtime.h>
#include <cstdint>
#include <cstddef>

typedef unsigned short u16;
typedef short bf16x8 __attribute__((ext_vector_type(8)));
typedef float f32x4 __attribute__((ext_vector_type(4)));

#define MFMA(a,b,c) __builtin_amdgcn_mfma_f32_16x16x32_bf16(a,b,c,0,0,0)

__device__ __forceinline__ u16 f2bf(float f) {
  unsigned u = __builtin_bit_cast(unsigned, f);
  u += 0x7fffu + ((u >> 16) & 1u);
  return (u16)(u >> 16);
}
__device__ __forceinline__ float bf2f(u16 b) {
  return __builtin_bit_cast(float, (unsigned)b << 16);
}
__device__ __forceinline__ void gl_lds16(const void* g, void* l) {
  __builtin_amdgcn_global_load_lds(
      (const __attribute__((address_space(1))) void*)g,
      (__attribute__((address_space(3))) void*)l, 16, 0, 0);
}
template <int N>
__device__ __forceinline__ void wait_vmcnt() {
  if constexpr (N == 0) asm volatile("s_waitcnt vmcnt(0)" ::: "memory");
  else if constexpr (N == 3) asm volatile("s_waitcnt vmcnt(3)" ::: "memory");
  else if constexpr (N == 4) asm volatile("s_waitcnt vmcnt(4)" ::: "memory");
}

// ---------------- f32 -> bf16 convert ----------------
__global__ __launch_bounds__(256) void cvt_bf16(const float* __restrict__ in,
                                                u16* __restrict__ out, int n) {
  int idx = (blockIdx.x * 256 + threadIdx.x) * 4;
  if (idx < n) {
    float4 v = *(const float4*)(in + idx);
    u16 o0 = f2bf(v.x), o1 = f2bf(v.y), o2 = f2bf(v.z), o3 = f2bf(v.w);
    ushort4 o = {o0, o1, o2, o3};
    *(ushort4*)(out + idx) = o;
  }
}

// ---------------- RoPE cos/sin table: [T=2048][64] f32 ----------------
__global__ __launch_bounds__(256) void rope_table(float* __restrict__ ctab,
                                                  float* __restrict__ stab) {
  int i = blockIdx.x * 256 + threadIdx.x;  // 0 .. 131071
  int t = i >> 6, f = i & 63;
  float inv_freq = powf(10000.0f, -(2.0f * f) / 128.0f);
  float ang = (float)t * inv_freq;
  ctab[i] = cosf(ang);
  stab[i] = sinf(ang);
}

// ---------------- deep-pipelined NT GEMM ----------------
// BK=32, triple-buffered LDS, 2-tiles-ahead prefetch, counted vmcnt, raw barriers.
// A[M,K] bf16 rm, B[N,K] bf16 rm -> C[M,N]. 512 threads (8 waves).
template <int BM, int BN, int OUT_F32>
__global__ __launch_bounds__(512, 2) void gemm_nt8(const u16* __restrict__ A,
                                                   const u16* __restrict__ Bw,
                                                   void* __restrict__ Cout,
                                                   int M, int N, int K) {
  constexpr int PHASES = (BM * BN == 65536) ? 2 : 1;  // 256x256 -> 2, else 1
  constexpr int WN = BN / 64;          // warps along N
  constexpr int WM = 8 / WN;           // warps along M
  constexpr int M_SUB = BM / WM;       // rows per wave (128 or 64)
  constexpr int M_REP = M_SUB / 16;    // 8 or 4
  constexpr int MRP = M_REP / PHASES;  // 4
  constexpr int ACH = BM / 128;        // A chunks per wave per tile (2 or 1)
  constexpr int BCH = BN / 128;        // B chunks per wave per tile
  constexpr int LPT = ACH + BCH;       // gl_lds per wave per tile (4 or 3)

  __shared__ u16 As[3][BM * 32];
  __shared__ u16 Bs[3][BN * 32];

  const int tid = threadIdx.x;
  const int lane = tid & 63;
  const int wv = tid >> 6;
  const int l16 = lane & 15, lhi = lane >> 4;
  const int wm = wv / WN, wn = wv % WN;
  const int m0 = blockIdx.y * BM;
  const int n0 = blockIdx.x * BN;
  const int nt = K >> 5;

  // staging lane geometry: chunk = 16 rows x 64B; lane l -> row l>>2, slot l&3
  const int srow = lane >> 2;
  const int scolb = ((lane & 3) * 16) ^ ((((lane >> 3) & 3)) << 4);  // pre-swizzled src col

  auto stageA = [&](int buf, int kt, int ch) {
    const char* src = (const char*)A +
        ((size_t)(m0 + ch * 16 + srow) * K + (size_t)kt * 32) * 2 + scolb;
    gl_lds16(src, (char*)As[buf] + ch * 1024);
  };
  auto stageB = [&](int buf, int kt, int ch) {
    const char* src = (const char*)Bw +
        ((size_t)(n0 + ch * 16 + srow) * K + (size_t)kt * 32) * 2 + scolb;
    gl_lds16(src, (char*)Bs[buf] + ch * 1024);
  };
  auto readA = [&](const u16* Ab, int mi) -> bf16x8 {
    int row = wm * M_SUB + mi * 16 + l16;
    return *(const bf16x8*)((const char*)Ab + row * 64 +
                            ((lhi * 16) ^ (((row >> 1) & 3) << 4)));
  };
  auto readB = [&](const u16* Bb, int ni) -> bf16x8 {
    int row = wn * 64 + ni * 16 + l16;
    return *(const bf16x8*)((const char*)Bb + row * 64 +
                            ((lhi * 16) ^ (((row >> 1) & 3) << 4)));
  };

  f32x4 acc[M_REP][4] = {};

  // prologue: stage tiles 0 and 1
#pragma unroll
  for (int i = 0; i < ACH; ++i) stageA(0, 0, wv + 8 * i);
#pragma unroll
  for (int i = 0; i < BCH; ++i) stageB(0, 0, wv + 8 * i);
#pragma unroll
  for (int i = 0; i < ACH; ++i) stageA(1, 1, wv + 8 * i);
#pragma unroll
  for (int i = 0; i < BCH; ++i) stageB(1, 1, wv + 8 * i);
  wait_vmcnt<LPT>();
  __builtin_amdgcn_sched_barrier(0);
  __builtin_amdgcn_s_barrier();
  __builtin_amdgcn_sched_barrier(0);

  int p = 0;
  for (int t = 0; t < nt; ++t) {
    const u16* Ab = As[p];
    const u16* Bb = Bs[p];
    int pb = p + 2; if (pb >= 3) pb -= 3;   // (t+2) % 3
    const bool do_stage = (t + 2 < nt);

    bf16x8 bfrag[4], afrag[MRP];
    // ---- phase 0: reads + stage ----
#pragma unroll
    for (int ni = 0; ni < 4; ++ni) bfrag[ni] = readB(Bb, ni);
#pragma unroll
    for (int mi = 0; mi < MRP; ++mi) afrag[mi] = readA(Ab, mi);
    if (do_stage) {
#pragma unroll
      for (int i = 0; i < ACH; i += PHASES) stageA(pb, t + 2, wv + 8 * i);
#pragma unroll
      for (int i = 0; i < BCH; i += PHASES) stageB(pb, t + 2, wv + 8 * i);
    }
    if (PHASES == 1) { if (do_stage) wait_vmcnt<LPT>(); else wait_vmcnt<0>(); }
    __builtin_amdgcn_sched_barrier(0);
    __builtin_amdgcn_s_barrier();
    __builtin_amdgcn_sched_barrier(0);
    __builtin_amdgcn_s_setprio(1);
#pragma unroll
    for (int mi = 0; mi < MRP; ++mi)
#pragma unroll
      for (int ni = 0; ni < 4; ++ni)
        acc[mi][ni] = MFMA(afrag[mi], bfrag[ni], acc[mi][ni]);
    __builtin_amdgcn_s_setprio(0);
    __builtin_amdgcn_sched_barrier(0);
    __builtin_amdgcn_s_barrier();
    __builtin_amdgcn_sched_barrier(0);

    if (PHASES == 2) {
      // ---- phase 1: reads (upper half of M) + stage + counted gate ----
#pragma unroll
      for (int mi = 0; mi < MRP; ++mi) afrag[mi] = readA(Ab, MRP + mi);
      if (do_stage) {
#pragma unroll
        for (int i = 1; i < ACH; i += PHASES) stageA(pb, t + 2, wv + 8 * i);
#pragma unroll
        for (int i = 1; i < BCH; i += PHASES) stageB(pb, t + 2, wv + 8 * i);
      }
      if (do_stage) wait_vmcnt<LPT>(); else wait_vmcnt<0>();
      __builtin_amdgcn_sched_barrier(0);
      __builtin_amdgcn_s_barrier();
      __builtin_amdgcn_sched_barrier(0);
      __builtin_amdgcn_s_setprio(1);
#pragma unroll
      for (int mi = 0; mi < MRP; ++mi)
#pragma unroll
        for (int ni = 0; ni < 4; ++ni)
          acc[MRP + mi][ni] = MFMA(afrag[mi], bfrag[ni], acc[MRP + mi][ni]);
      __builtin_amdgcn_s_setprio(0);
      __builtin_amdgcn_sched_barrier(0);
      __builtin_amdgcn_s_barrier();
      __builtin_amdgcn_sched_barrier(0);
    }
    p = (p + 1 == 3) ? 0 : p + 1;
  }

  // epilogue
#pragma unroll
  for (int mi = 0; mi < M_REP; ++mi)
#pragma unroll
    for (int ni = 0; ni < 4; ++ni) {
      int col = n0 + wn * 64 + ni * 16 + l16;
#pragma unroll
      for (int j = 0; j < 4; ++j) {
        int row = m0 + wm * M_SUB + mi * 16 + lhi * 4 + j;
        float v = acc[mi][ni][j];
        if (OUT_F32)
          ((float*)Cout)[(size_t)row * N + col] = v;
        else
          ((u16*)Cout)[(size_t)row * N + col] = f2bf(v);
      }
    }
}

// ---------------- RoPE + L2 norm + gamma ----------------
template <int NH>
__global__ __launch_bounds__(256) void rope_norm(const u16* __restrict__ raw,
                                                 u16* __restrict__ out,
                                                 const float* __restrict__ ctab,
                                                 const float* __restrict__ stab,
                                                 const float* __restrict__ gamma,
                                                 int stride, int coloff, float scale) {
  int gw = blockIdx.x * 4 + (threadIdx.x >> 6);
  int lane = threadIdx.x & 63;
  int h = gw & (NH - 1);
  int bt = gw / NH;               // 0..4095
  int t = bt & 2047, b = bt >> 11;
  const u16* r = raw + (size_t)bt * stride + coloff + (size_t)h * 128;
  float q1 = bf2f(r[lane]), q2 = bf2f(r[lane + 64]);
  float c = ctab[t * 64 + lane], s = stab[t * 64 + lane];
  float e1 = q1 * c - q2 * s;
  float e2 = q2 * c + q1 * s;
  float ss = e1 * e1 + e2 * e2;
#pragma unroll
  for (int off = 1; off < 64; off <<= 1) ss += __shfl_xor(ss, off);
  float inv = scale / (sqrtf(ss) + 1e-6f);
  size_t ob = (((size_t)(b * NH + h)) * 2048 + t) * 128;
  out[ob + lane]      = f2bf(e1 * inv * gamma[lane]);
  out[ob + lane + 64] = f2bf(e2 * inv * gamma[lane + 64]);
}

// ---------------- V transpose: qkv[B*T,3072] cols 2560.. -> [B, HK, 128, T] ----------------
__global__ __launch_bounds__(256) void transpose_v(const u16* __restrict__ qkv,
                                                   u16* __restrict__ vt) {
  __shared__ u16 tile[32][33];
  int t0 = blockIdx.x * 32, d0 = blockIdx.y * 32;
  int bh = blockIdx.z;
  int b = bh >> 2, hkk = bh & 3;
  int tx = threadIdx.x & 31, ty = threadIdx.x >> 5;  // ty 0..7
#pragma unroll
  for (int i = 0; i < 4; ++i) {
    int r = ty + i * 8;
    tile[r][tx] = qkv[((size_t)(b * 2048 + t0 + r)) * 3072 + 2560 + hkk * 128 + d0 + tx];
  }
  __syncthreads();
#pragma unroll
  for (int i = 0; i < 4; ++i) {
    int r = ty + i * 8;
    vt[((size_t)((b * 4 + hkk) * 128 + d0 + r)) * 2048 + t0 + tx] = tile[tx][r];
  }
}

// ---------------- flash attention, sliding window 1024, KVBLK=64, double-buffered ----------------
// grid: (T/64, B*H); block 256 (4 waves, 16 q-rows each)
__global__ __launch_bounds__(256) void attn_kernel(const u16* __restrict__ Qr,
                                                   const u16* __restrict__ Kr,
                                                   const u16* __restrict__ Vt,
                                                   u16* __restrict__ Yt) {
  __shared__ u16 Ks[2][64 * 128];   // 16KB each, XOR-swizzled 256B rows
  __shared__ u16 Vs[2][128 * 64];   // 16KB each, XOR-swizzled 128B rows, [d][s]
  __shared__ u16 Ps[4][16 * 64];    // per-wave P, XOR-swizzled 128B rows
  const int tid = threadIdx.x;
  const int lane = tid & 63;
  const int wv = tid >> 6;
  const int l16 = lane & 15, lhi = lane >> 4;
  const int bh = blockIdx.y;
  const int b = bh >> 4, h = bh & 15;
  const int hk = h >> 2;
  const int q0b = blockIdx.x * 64;
  const int q0w = q0b + wv * 16;

  const u16* qbase = Qr + (((size_t)bh) * 2048 + q0w + l16) * 128;
  bf16x8 qf[4];
#pragma unroll
  for (int dc = 0; dc < 4; ++dc)
    qf[dc] = *(const bf16x8*)(qbase + dc * 32 + lhi * 8);

  const char* kg = (const char*)(Kr + ((size_t)(b * 4 + hk)) * 2048 * 128);
  const u16* vg = Vt + ((size_t)(b * 4 + hk)) * 2048 * 128;  // [128][2048]

  auto stage = [&](int buf, int s0) {
#pragma unroll
    for (int i = 0; i < 4; ++i) {
      int c = wv + 4 * i;
      int row = c * 4 + lhi;
      int srcb = (l16 * 16) ^ ((row & 7) << 4);
      gl_lds16(kg + (size_t)(s0 + row) * 256 + srcb, (char*)Ks[buf] + c * 1024);
    }
    int r8 = lane >> 3, c8 = lane & 7;
#pragma unroll
    for (int i = 0; i < 4; ++i) {
      int c = wv + 4 * i;
      int row = c * 8 + r8;
      int srcb = (c8 * 16) ^ ((r8 & 7) << 4);
      gl_lds16((const char*)(vg + (size_t)row * 2048 + s0) + srcb,
               (char*)Vs[buf] + c * 1024);
    }
  };

  float msub[4] = {0.f, 0.f, 0.f, 0.f};
  float l_r[4] = {0.f, 0.f, 0.f, 0.f};
  f32x4 oacc[8] = {};

  int s_lo = q0b - 1024; if (s_lo < 0) s_lo = 0;
  const int nt = (q0b + 64 - s_lo) >> 6;

  stage(0, s_lo);
  __syncthreads();
  int cur = 0;
  for (int it = 0; it < nt; ++it) {
    const int s0 = s_lo + (it << 6);
    if (it + 1 < nt) stage(cur ^ 1, s0 + 64);
    // QK^T (16 MFMA)
    f32x4 sacc[4] = {};
    const char* ksb = (const char*)Ks[cur];
    __builtin_amdgcn_s_setprio(1);
#pragma unroll
    for (int n = 0; n < 4; ++n) {
      int row = n * 16 + l16;
#pragma unroll
      for (int dc = 0; dc < 4; ++dc) {
        bf16x8 kf = *(const bf16x8*)(ksb + row * 256 +
                                     ((dc * 64 + lhi * 16) ^ ((l16 & 7) << 4)));
        sacc[n] = MFMA(qf[dc], kf, sacc[n]);
      }
    }
    __builtin_amdgcn_s_setprio(0);
    float sval[4][4];
    float mt[4] = {-INFINITY, -INFINITY, -INFINITY, -INFINITY};
#pragma unroll
    for (int n = 0; n < 4; ++n)
#pragma unroll
      for (int j = 0; j < 4; ++j) {
        int q = q0w + lhi * 4 + j;
        int s = s0 + n * 16 + l16;
        float v = sacc[n][j];
        if ((unsigned)(q - s) > 1024u) v = -INFINITY;
        sval[n][j] = v;
        mt[j] = fmaxf(mt[j], v);
      }
#pragma unroll
    for (int off = 1; off < 16; off <<= 1)
#pragma unroll
      for (int j = 0; j < 4; ++j)
        mt[j] = fmaxf(mt[j], __shfl_xor(mt[j], off));
    bool need = false;
#pragma unroll
    for (int j = 0; j < 4; ++j) need = need || (mt[j] > msub[j] + 8.f);
    if (__any(need)) {
#pragma unroll
      for (int j = 0; j < 4; ++j) {
        float nb = fmaxf(msub[j], mt[j]);
        float sc2 = __expf(msub[j] - nb);
        l_r[j] *= sc2;
#pragma unroll
        for (int dt = 0; dt < 8; ++dt) oacc[dt][j] *= sc2;
        msub[j] = nb;
      }
    }
    char* psb = (char*)Ps[wv];
    float rs[4] = {0.f, 0.f, 0.f, 0.f};
#pragma unroll
    for (int n = 0; n < 4; ++n)
#pragma unroll
      for (int j = 0; j < 4; ++j) {
        float p = __expf(sval[n][j] - msub[j]);
        rs[j] += p;
        int R = lhi * 4 + j;
        *(u16*)(psb + R * 128 + (((n * 16 + l16) * 2) ^ ((R & 7) << 4))) = f2bf(p);
      }
#pragma unroll
    for (int off = 1; off < 16; off <<= 1)
#pragma unroll
      for (int j = 0; j < 4; ++j) rs[j] += __shfl_xor(rs[j], off);
#pragma unroll
    for (int j = 0; j < 4; ++j) l_r[j] += rs[j];
    // PV (16 MFMA)
    bf16x8 pf[2];
#pragma unroll
    for (int kk = 0; kk < 2; ++kk)
      pf[kk] = *(const bf16x8*)(psb + l16 * 128 +
                                ((kk * 64 + lhi * 16) ^ ((l16 & 7) << 4)));
    const char* vsb = (const char*)Vs[cur];
    __builtin_amdgcn_s_setprio(1);
#pragma unroll
    for (int dt = 0; dt < 8; ++dt) {
      int row = dt * 16 + l16;
#pragma unroll
      for (int kk = 0; kk < 2; ++kk) {
        bf16x8 vf = *(const bf16x8*)(vsb + row * 128 +
                                     ((kk * 64 + lhi * 16) ^ ((l16 & 7) << 4)));
        oacc[dt] = MFMA(pf[kk], vf, oacc[dt]);
      }
    }
    __builtin_amdgcn_s_setprio(0);
    __syncthreads();
    cur ^= 1;
  }
#pragma unroll
  for (int j = 0; j < 4; ++j) {
    float inv = 1.0f / l_r[j];
    int q = q0w + lhi * 4 + j;
    size_t rowbase = ((size_t)(b * 2048 + q)) * 2048 + (size_t)h * 128;
#pragma unroll
    for (int dt = 0; dt < 8; ++dt)
      Yt[rowbase + dt * 16 + l16] = f2bf(oacc[dt][j] * inv);
  }
}

extern "C" void kernel_launch(void* const* d_in, const int* in_sizes, int n_in,
                              void* d_out, int out_size, void* d_ws, size_t ws_size,
                              hipStream_t stream) {
  (void)in_sizes; (void)n_in; (void)out_size; (void)ws_size;
  const float* x  = (const float*)d_in[0];
  const float* wq = (const float*)d_in[1];
  const float* wk = (const float*)d_in[2];
  const float* wv = (const float*)d_in[3];
  const float* wo = (const float*)d_in[4];
  const float* gq = (const float*)d_in[5];
  const float* gk = (const float*)d_in[6];
  float* out = (float*)d_out;
  char* ws = (char*)d_ws;

  size_t off = 0;
  auto alloc = [&](size_t bytes) {
    size_t o = off;
    off += (bytes + 255) & ~(size_t)255;
    return o;
  };
  u16* xb     = (u16*)(ws + alloc((size_t)4096 * 2048 * 2));
  u16* wqkvb  = (u16*)(ws + alloc((size_t)3072 * 2048 * 2));
  u16* wob    = (u16*)(ws + alloc((size_t)2048 * 2048 * 2));
  u16* qkvraw = (u16*)(ws + alloc((size_t)4096 * 3072 * 2));  // later reused as ytmp
  u16* qr     = (u16*)(ws + alloc((size_t)4096 * 2048 * 2));
  u16* kr     = (u16*)(ws + alloc((size_t)4096 * 512 * 2));
  u16* vt     = (u16*)(ws + alloc((size_t)4096 * 512 * 2));
  float* ctab = (float*)(ws + alloc((size_t)2048 * 64 * 4));
  float* stab = (float*)(ws + alloc((size_t)2048 * 64 * 4));
  u16* ytmp = qkvraw;  // safe: qkvraw fully consumed before attn writes

  const float sc = 0.08838834764831845f;  // 1/sqrt(128)

  cvt_bf16<<<8192, 256, 0, stream>>>(x, xb, 8388608);
  cvt_bf16<<<4096, 256, 0, stream>>>(wq, wqkvb, 4194304);
  cvt_bf16<<<1024, 256, 0, stream>>>(wk, wqkvb + 4194304, 1048576);
  cvt_bf16<<<1024, 256, 0, stream>>>(wv, wqkvb + 4194304 + 1048576, 1048576);
  cvt_bf16<<<4096, 256, 0, stream>>>(wo, wob, 4194304);
  rope_table<<<512, 256, 0, stream>>>(ctab, stab);

  // fused QKV projection: [4096,2048] x [3072,2048]^T -> [4096,3072]
  gemm_nt8<256, 256, 0><<<dim3(12, 16), 512, 0, stream>>>(xb, wqkvb, qkvraw, 4096, 3072, 2048);

  rope_norm<16><<<16384, 256, 0, stream>>>(qkvraw, qr, ctab, stab, gq, 3072, 0, sc);
  rope_norm<4><<<4096, 256, 0, stream>>>(qkvraw, kr, ctab, stab, gk, 3072, 2048, 1.0f);
  transpose_v<<<dim3(64, 4, 8), 256, 0, stream>>>(qkvraw, vt);

  attn_kernel<<<dim3(32, 32), 256, 0, stream>>>(qr, kr, vt, ytmp);

  // output projection (f32 out): 256x128 tiles -> 256 blocks (1/CU)
  gemm_nt8<256, 128, 1><<<dim3(16, 16), 512, 0, stream>>>(ytmp, wob, out, 4096, 2048, 2048);
}

// Round 4
// 227.019 us; speedup vs baseline: 1.5862x; 1.0893x over previous
//
#include <hip/hip_runtime.h>
#include <cstdint>
#include <cstddef>

typedef unsigned short u16;
typedef short bf16x8 __attribute__((ext_vector_type(8)));
typedef float f32x4 __attribute__((ext_vector_type(4)));

#define MFMA(a,b,c) __builtin_amdgcn_mfma_f32_16x16x32_bf16(a,b,c,0,0,0)

__device__ __forceinline__ u16 f2bf(float f) {
  unsigned u = __builtin_bit_cast(unsigned, f);
  u += 0x7fffu + ((u >> 16) & 1u);
  return (u16)(u >> 16);
}
__device__ __forceinline__ float bf2f(u16 b) {
  return __builtin_bit_cast(float, (unsigned)b << 16);
}
__device__ __forceinline__ float exp2_hw(float x) {
  float r;
  asm("v_exp_f32 %0, %1" : "=v"(r) : "v"(x));
  return r;
}
__device__ __forceinline__ void gl_lds16(const void* g, void* l) {
  __builtin_amdgcn_global_load_lds(
      (const __attribute__((address_space(1))) void*)g,
      (__attribute__((address_space(3))) void*)l, 16, 0, 0);
}
template <int N>
__device__ __forceinline__ void wait_vmcnt() {
  if constexpr (N == 0) asm volatile("s_waitcnt vmcnt(0)" ::: "memory");
  else if constexpr (N == 3) asm volatile("s_waitcnt vmcnt(3)" ::: "memory");
  else if constexpr (N == 4) asm volatile("s_waitcnt vmcnt(4)" ::: "memory");
}

// ---------------- fused f32 -> bf16 convert for all 5 inputs ----------------
__global__ __launch_bounds__(256) void cvt_all(const float* __restrict__ x,
                                               const float* __restrict__ wq,
                                               const float* __restrict__ wk,
                                               const float* __restrict__ wv,
                                               const float* __restrict__ wo,
                                               u16* __restrict__ xb,
                                               u16* __restrict__ wqkvb,
                                               u16* __restrict__ wob) {
  int idx = (blockIdx.x * 256 + threadIdx.x) * 4;
  const float* src;
  u16* dst;
  if (idx < 8388608) { src = x + idx; dst = xb + idx; }
  else if (idx < 12582912) { src = wq + (idx - 8388608); dst = wqkvb + (idx - 8388608); }
  else if (idx < 13631488) { src = wk + (idx - 12582912); dst = wqkvb + (idx - 8388608); }
  else if (idx < 14680064) { src = wv + (idx - 13631488); dst = wqkvb + (idx - 8388608); }
  else if (idx < 18874368) { src = wo + (idx - 14680064); dst = wob + (idx - 14680064); }
  else return;
  float4 v = *(const float4*)src;
  ushort4 o = {f2bf(v.x), f2bf(v.y), f2bf(v.z), f2bf(v.w)};
  *(ushort4*)dst = o;
}

// ---------------- RoPE cos/sin table: [T=2048][64] f32 ----------------
__global__ __launch_bounds__(256) void rope_table(float* __restrict__ ctab,
                                                  float* __restrict__ stab) {
  int i = blockIdx.x * 256 + threadIdx.x;  // 0 .. 131071
  int t = i >> 6, f = i & 63;
  float inv_freq = powf(10000.0f, -(2.0f * f) / 128.0f);
  float ang = (float)t * inv_freq;
  ctab[i] = cosf(ang);
  stab[i] = sinf(ang);
}

// ---------------- deep-pipelined NT GEMM ----------------
// BK=32, triple-buffered LDS, 2-tiles-ahead prefetch, counted vmcnt, raw barriers.
template <int BM, int BN, int OUT_F32>
__global__ __launch_bounds__(512, 2) void gemm_nt8(const u16* __restrict__ A,
                                                   const u16* __restrict__ Bw,
                                                   void* __restrict__ Cout,
                                                   int M, int N, int K) {
  constexpr int PHASES = (BM * BN == 65536) ? 2 : 1;
  constexpr int WN = BN / 64;
  constexpr int WM = 8 / WN;
  constexpr int M_SUB = BM / WM;
  constexpr int M_REP = M_SUB / 16;
  constexpr int MRP = M_REP / PHASES;
  constexpr int ACH = BM / 128;
  constexpr int BCH = BN / 128;
  constexpr int LPT = ACH + BCH;

  __shared__ u16 As[3][BM * 32];
  __shared__ u16 Bs[3][BN * 32];

  const int tid = threadIdx.x;
  const int lane = tid & 63;
  const int wv = tid >> 6;
  const int l16 = lane & 15, lhi = lane >> 4;
  const int wm = wv / WN, wn = wv % WN;
  const int m0 = blockIdx.y * BM;
  const int n0 = blockIdx.x * BN;
  const int nt = K >> 5;

  const int srow = lane >> 2;
  const int scolb = ((lane & 3) * 16) ^ ((((lane >> 3) & 3)) << 4);

  auto stageA = [&](int buf, int kt, int ch) {
    const char* src = (const char*)A +
        ((size_t)(m0 + ch * 16 + srow) * K + (size_t)kt * 32) * 2 + scolb;
    gl_lds16(src, (char*)As[buf] + ch * 1024);
  };
  auto stageB = [&](int buf, int kt, int ch) {
    const char* src = (const char*)Bw +
        ((size_t)(n0 + ch * 16 + srow) * K + (size_t)kt * 32) * 2 + scolb;
    gl_lds16(src, (char*)Bs[buf] + ch * 1024);
  };
  auto readA = [&](const u16* Ab, int mi) -> bf16x8 {
    int row = wm * M_SUB + mi * 16 + l16;
    return *(const bf16x8*)((const char*)Ab + row * 64 +
                            ((lhi * 16) ^ (((row >> 1) & 3) << 4)));
  };
  auto readB = [&](const u16* Bb, int ni) -> bf16x8 {
    int row = wn * 64 + ni * 16 + l16;
    return *(const bf16x8*)((const char*)Bb + row * 64 +
                            ((lhi * 16) ^ (((row >> 1) & 3) << 4)));
  };

  f32x4 acc[M_REP][4] = {};

#pragma unroll
  for (int i = 0; i < ACH; ++i) stageA(0, 0, wv + 8 * i);
#pragma unroll
  for (int i = 0; i < BCH; ++i) stageB(0, 0, wv + 8 * i);
#pragma unroll
  for (int i = 0; i < ACH; ++i) stageA(1, 1, wv + 8 * i);
#pragma unroll
  for (int i = 0; i < BCH; ++i) stageB(1, 1, wv + 8 * i);
  wait_vmcnt<LPT>();
  __builtin_amdgcn_sched_barrier(0);
  __builtin_amdgcn_s_barrier();
  __builtin_amdgcn_sched_barrier(0);

  int p = 0;
  for (int t = 0; t < nt; ++t) {
    const u16* Ab = As[p];
    const u16* Bb = Bs[p];
    int pb = p + 2; if (pb >= 3) pb -= 3;
    const bool do_stage = (t + 2 < nt);

    bf16x8 bfrag[4], afrag[MRP];
#pragma unroll
    for (int ni = 0; ni < 4; ++ni) bfrag[ni] = readB(Bb, ni);
#pragma unroll
    for (int mi = 0; mi < MRP; ++mi) afrag[mi] = readA(Ab, mi);
    if (do_stage) {
#pragma unroll
      for (int i = 0; i < ACH; i += PHASES) stageA(pb, t + 2, wv + 8 * i);
#pragma unroll
      for (int i = 0; i < BCH; i += PHASES) stageB(pb, t + 2, wv + 8 * i);
    }
    if (PHASES == 1) { if (do_stage) wait_vmcnt<LPT>(); else wait_vmcnt<0>(); }
    __builtin_amdgcn_sched_barrier(0);
    __builtin_amdgcn_s_barrier();
    __builtin_amdgcn_sched_barrier(0);
    __builtin_amdgcn_s_setprio(1);
#pragma unroll
    for (int mi = 0; mi < MRP; ++mi)
#pragma unroll
      for (int ni = 0; ni < 4; ++ni)
        acc[mi][ni] = MFMA(afrag[mi], bfrag[ni], acc[mi][ni]);
    __builtin_amdgcn_s_setprio(0);
    __builtin_amdgcn_sched_barrier(0);
    __builtin_amdgcn_s_barrier();
    __builtin_amdgcn_sched_barrier(0);

    if (PHASES == 2) {
#pragma unroll
      for (int mi = 0; mi < MRP; ++mi) afrag[mi] = readA(Ab, MRP + mi);
      if (do_stage) {
#pragma unroll
        for (int i = 1; i < ACH; i += PHASES) stageA(pb, t + 2, wv + 8 * i);
#pragma unroll
        for (int i = 1; i < BCH; i += PHASES) stageB(pb, t + 2, wv + 8 * i);
      }
      if (do_stage) wait_vmcnt<LPT>(); else wait_vmcnt<0>();
      __builtin_amdgcn_sched_barrier(0);
      __builtin_amdgcn_s_barrier();
      __builtin_amdgcn_sched_barrier(0);
      __builtin_amdgcn_s_setprio(1);
#pragma unroll
      for (int mi = 0; mi < MRP; ++mi)
#pragma unroll
        for (int ni = 0; ni < 4; ++ni)
          acc[MRP + mi][ni] = MFMA(afrag[mi], bfrag[ni], acc[MRP + mi][ni]);
      __builtin_amdgcn_s_setprio(0);
      __builtin_amdgcn_sched_barrier(0);
      __builtin_amdgcn_s_barrier();
      __builtin_amdgcn_sched_barrier(0);
    }
    p = (p + 1 == 3) ? 0 : p + 1;
  }

#pragma unroll
  for (int mi = 0; mi < M_REP; ++mi)
#pragma unroll
    for (int ni = 0; ni < 4; ++ni) {
      int col = n0 + wn * 64 + ni * 16 + l16;
#pragma unroll
      for (int j = 0; j < 4; ++j) {
        int row = m0 + wm * M_SUB + mi * 16 + lhi * 4 + j;
        float v = acc[mi][ni][j];
        if (OUT_F32)
          ((float*)Cout)[(size_t)row * N + col] = v;
        else
          ((u16*)Cout)[(size_t)row * N + col] = f2bf(v);
      }
    }
}

// ---------------- RoPE + L2 norm + gamma ----------------
template <int NH>
__global__ __launch_bounds__(256) void rope_norm(const u16* __restrict__ raw,
                                                 u16* __restrict__ out,
                                                 const float* __restrict__ ctab,
                                                 const float* __restrict__ stab,
                                                 const float* __restrict__ gamma,
                                                 int stride, int coloff, float scale) {
  int gw = blockIdx.x * 4 + (threadIdx.x >> 6);
  int lane = threadIdx.x & 63;
  int h = gw & (NH - 1);
  int bt = gw / NH;               // 0..4095
  int t = bt & 2047, b = bt >> 11;
  const u16* r = raw + (size_t)bt * stride + coloff + (size_t)h * 128;
  float q1 = bf2f(r[lane]), q2 = bf2f(r[lane + 64]);
  float c = ctab[t * 64 + lane], s = stab[t * 64 + lane];
  float e1 = q1 * c - q2 * s;
  float e2 = q2 * c + q1 * s;
  float ss = e1 * e1 + e2 * e2;
#pragma unroll
  for (int off = 1; off < 64; off <<= 1) ss += __shfl_xor(ss, off);
  float inv = scale / (sqrtf(ss) + 1e-6f);
  size_t ob = (((size_t)(b * NH + h)) * 2048 + t) * 128;
  out[ob + lane]      = f2bf(e1 * inv * gamma[lane]);
  out[ob + lane + 64] = f2bf(e2 * inv * gamma[lane + 64]);
}

// ---------------- V transpose: qkv[B*T,3072] cols 2560.. -> [B, HK, 128, T] ----------------
__global__ __launch_bounds__(256) void transpose_v(const u16* __restrict__ qkv,
                                                   u16* __restrict__ vt) {
  __shared__ u16 tile[32][33];
  int t0 = blockIdx.x * 32, d0 = blockIdx.y * 32;
  int bh = blockIdx.z;
  int b = bh >> 2, hkk = bh & 3;
  int tx = threadIdx.x & 31, ty = threadIdx.x >> 5;  // ty 0..7
#pragma unroll
  for (int i = 0; i < 4; ++i) {
    int r = ty + i * 8;
    tile[r][tx] = qkv[((size_t)(b * 2048 + t0 + r)) * 3072 + 2560 + hkk * 128 + d0 + tx];
  }
  __syncthreads();
#pragma unroll
  for (int i = 0; i < 4; ++i) {
    int r = ty + i * 8;
    vt[((size_t)((b * 4 + hkk) * 128 + d0 + r)) * 2048 + t0 + tx] = tile[tx][r];
  }
}

// ---------------- flash attention, sliding window 1024, KVBLK=64, double-buffered ----------------
// log2-domain softmax (log2e folded into Q), mask only on first/last tiles,
// rowsum via ones-MFMA. grid: (T/64, B*H); block 256 (4 waves, 16 q-rows each)
__global__ __launch_bounds__(256) void attn_kernel(const u16* __restrict__ Qr,
                                                   const u16* __restrict__ Kr,
                                                   const u16* __restrict__ Vt,
                                                   u16* __restrict__ Yt) {
  __shared__ u16 Ks[2][64 * 128];   // XOR-swizzled 256B rows
  __shared__ u16 Vs[2][128 * 64];   // XOR-swizzled 128B rows, [d][s]
  __shared__ u16 Ps[4][16 * 64];    // per-wave P, XOR-swizzled 128B rows
  const int tid = threadIdx.x;
  const int lane = tid & 63;
  const int wv = tid >> 6;
  const int l16 = lane & 15, lhi = lane >> 4;
  const int bh = blockIdx.y;
  const int b = bh >> 4, h = bh & 15;
  const int hk = h >> 2;
  const int q0b = blockIdx.x * 64;
  const int q0w = q0b + wv * 16;

  const u16* qbase = Qr + (((size_t)bh) * 2048 + q0w + l16) * 128;
  bf16x8 qf[4];
#pragma unroll
  for (int dc = 0; dc < 4; ++dc)
    qf[dc] = *(const bf16x8*)(qbase + dc * 32 + lhi * 8);

  const char* kg = (const char*)(Kr + ((size_t)(b * 4 + hk)) * 2048 * 128);
  const u16* vg = Vt + ((size_t)(b * 4 + hk)) * 2048 * 128;  // [128][2048]

  auto stage = [&](int buf, int s0) {
#pragma unroll
    for (int i = 0; i < 4; ++i) {
      int c = wv + 4 * i;
      int row = c * 4 + lhi;
      int srcb = (l16 * 16) ^ ((row & 7) << 4);
      gl_lds16(kg + (size_t)(s0 + row) * 256 + srcb, (char*)Ks[buf] + c * 1024);
    }
    int r8 = lane >> 3, c8 = lane & 7;
#pragma unroll
    for (int i = 0; i < 4; ++i) {
      int c = wv + 4 * i;
      int row = c * 8 + r8;
      int srcb = (c8 * 16) ^ ((r8 & 7) << 4);
      gl_lds16((const char*)(vg + (size_t)row * 2048 + s0) + srcb,
               (char*)Vs[buf] + c * 1024);
    }
  };

  const bf16x8 ones = {0x3F80, 0x3F80, 0x3F80, 0x3F80, 0x3F80, 0x3F80, 0x3F80, 0x3F80};
  float msub[4] = {0.f, 0.f, 0.f, 0.f};
  f32x4 lacc = {};
  f32x4 oacc[8] = {};

  int s_lo = q0b - 1024; if (s_lo < 0) s_lo = 0;
  const int nt = (q0b + 64 - s_lo) >> 6;

  stage(0, s_lo);
  __syncthreads();
  int cur = 0;
  for (int it = 0; it < nt; ++it) {
    const int s0 = s_lo + (it << 6);
    if (it + 1 < nt) stage(cur ^ 1, s0 + 64);
    // QK^T (16 MFMA)
    f32x4 sacc[4] = {};
    const char* ksb = (const char*)Ks[cur];
    __builtin_amdgcn_s_setprio(1);
#pragma unroll
    for (int n = 0; n < 4; ++n) {
      int row = n * 16 + l16;
#pragma unroll
      for (int dc = 0; dc < 4; ++dc) {
        bf16x8 kf = *(const bf16x8*)(ksb + row * 256 +
                                     ((dc * 64 + lhi * 16) ^ ((l16 & 7) << 4)));
        sacc[n] = MFMA(qf[dc], kf, sacc[n]);
      }
    }
    __builtin_amdgcn_s_setprio(0);
    // mask only first (window edge) and last (causal edge) tiles
    const bool domask = (it == nt - 1) || (it == 0 && q0b >= 1024);
    if (domask) {
#pragma unroll
      for (int n = 0; n < 4; ++n)
#pragma unroll
        for (int j = 0; j < 4; ++j) {
          int q = q0w + lhi * 4 + j;
          int s = s0 + n * 16 + l16;
          if ((unsigned)(q - s) > 1024u) sacc[n][j] = -INFINITY;
        }
    }
    // tile max (scores are log2-domain)
    float mt[4] = {-INFINITY, -INFINITY, -INFINITY, -INFINITY};
#pragma unroll
    for (int n = 0; n < 4; ++n)
#pragma unroll
      for (int j = 0; j < 4; ++j) mt[j] = fmaxf(mt[j], sacc[n][j]);
#pragma unroll
    for (int off = 1; off < 16; off <<= 1)
#pragma unroll
      for (int j = 0; j < 4; ++j)
        mt[j] = fmaxf(mt[j], __shfl_xor(mt[j], off));
    // deferred rescale (threshold 8 in log2 units -> p <= 256)
    bool need = false;
#pragma unroll
    for (int j = 0; j < 4; ++j) need = need || (mt[j] > msub[j] + 8.f);
    if (__any(need)) {
#pragma unroll
      for (int j = 0; j < 4; ++j) {
        float nb = fmaxf(msub[j], mt[j]);
        float sc2 = exp2_hw(msub[j] - nb);
        lacc[j] *= sc2;
#pragma unroll
        for (int dt = 0; dt < 8; ++dt) oacc[dt][j] *= sc2;
        msub[j] = nb;
      }
    }
    // p = 2^(s - base), write swizzled to per-wave LDS
    char* psb = (char*)Ps[wv];
#pragma unroll
    for (int n = 0; n < 4; ++n)
#pragma unroll
      for (int j = 0; j < 4; ++j) {
        float p = exp2_hw(sacc[n][j] - msub[j]);
        int R = lhi * 4 + j;
        *(u16*)(psb + R * 128 + (((n * 16 + l16) * 2) ^ ((R & 7) << 4))) = f2bf(p);
      }
    // PV + rowsum (18 MFMA)
    bf16x8 pf[2];
#pragma unroll
    for (int kk = 0; kk < 2; ++kk)
      pf[kk] = *(const bf16x8*)(psb + l16 * 128 +
                                ((kk * 64 + lhi * 16) ^ ((l16 & 7) << 4)));
    const char* vsb = (const char*)Vs[cur];
    __builtin_amdgcn_s_setprio(1);
    lacc = MFMA(pf[0], ones, lacc);
    lacc = MFMA(pf[1], ones, lacc);
#pragma unroll
    for (int dt = 0; dt < 8; ++dt) {
      int row = dt * 16 + l16;
#pragma unroll
      for (int kk = 0; kk < 2; ++kk) {
        bf16x8 vf = *(const bf16x8*)(vsb + row * 128 +
                                     ((kk * 64 + lhi * 16) ^ ((l16 & 7) << 4)));
        oacc[dt] = MFMA(pf[kk], vf, oacc[dt]);
      }
    }
    __builtin_amdgcn_s_setprio(0);
    __syncthreads();
    cur ^= 1;
  }
#pragma unroll
  for (int j = 0; j < 4; ++j) {
    float inv = 1.0f / lacc[j];
    int q = q0w + lhi * 4 + j;
    size_t rowbase = ((size_t)(b * 2048 + q)) * 2048 + (size_t)h * 128;
#pragma unroll
    for (int dt = 0; dt < 8; ++dt)
      Yt[rowbase + dt * 16 + l16] = f2bf(oacc[dt][j] * inv);
  }
}

extern "C" void kernel_launch(void* const* d_in, const int* in_sizes, int n_in,
                              void* d_out, int out_size, void* d_ws, size_t ws_size,
                              hipStream_t stream) {
  (void)in_sizes; (void)n_in; (void)out_size; (void)ws_size;
  const float* x  = (const float*)d_in[0];
  const float* wq = (const float*)d_in[1];
  const float* wk = (const float*)d_in[2];
  const float* wv = (const float*)d_in[3];
  const float* wo = (const float*)d_in[4];
  const float* gq = (const float*)d_in[5];
  const float* gk = (const float*)d_in[6];
  float* out = (float*)d_out;
  char* ws = (char*)d_ws;

  size_t off = 0;
  auto alloc = [&](size_t bytes) {
    size_t o = off;
    off += (bytes + 255) & ~(size_t)255;
    return o;
  };
  u16* xb     = (u16*)(ws + alloc((size_t)4096 * 2048 * 2));
  u16* wqkvb  = (u16*)(ws + alloc((size_t)3072 * 2048 * 2));
  u16* wob    = (u16*)(ws + alloc((size_t)2048 * 2048 * 2));
  u16* qkvraw = (u16*)(ws + alloc((size_t)4096 * 3072 * 2));  // later reused as ytmp
  u16* qr     = (u16*)(ws + alloc((size_t)4096 * 2048 * 2));
  u16* kr     = (u16*)(ws + alloc((size_t)4096 * 512 * 2));
  u16* vt     = (u16*)(ws + alloc((size_t)4096 * 512 * 2));
  float* ctab = (float*)(ws + alloc((size_t)2048 * 64 * 4));
  float* stab = (float*)(ws + alloc((size_t)2048 * 64 * 4));
  u16* ytmp = qkvraw;  // safe: qkvraw fully consumed before attn writes

  // 1/sqrt(128) * log2(e): Q scale folded so scores are in log2 domain
  const float sc_log2 = 0.12751744f;

  cvt_all<<<18432, 256, 0, stream>>>(x, wq, wk, wv, wo, xb, wqkvb, wob);
  rope_table<<<512, 256, 0, stream>>>(ctab, stab);

  // fused QKV projection: [4096,2048] x [3072,2048]^T -> [4096,3072]
  gemm_nt8<256, 256, 0><<<dim3(12, 16), 512, 0, stream>>>(xb, wqkvb, qkvraw, 4096, 3072, 2048);

  rope_norm<16><<<16384, 256, 0, stream>>>(qkvraw, qr, ctab, stab, gq, 3072, 0, sc_log2);
  rope_norm<4><<<4096, 256, 0, stream>>>(qkvraw, kr, ctab, stab, gk, 3072, 2048, 1.0f);
  transpose_v<<<dim3(64, 4, 8), 256, 0, stream>>>(qkvraw, vt);

  attn_kernel<<<dim3(32, 32), 256, 0, stream>>>(qr, kr, vt, ytmp);

  // output projection (f32 out): 256x128 tiles -> 256 blocks (1/CU)
  gemm_nt8<256, 128, 1><<<dim3(16, 16), 512, 0, stream>>>(ytmp, wob, out, 4096, 2048, 2048);
}